// Round 2
// baseline (169.628 us; speedup 1.0000x reference)
//
#include <hip/hip_runtime.h>

#define BB 8
#define SS 2048
#define EE 512
#define HD 64

typedef __attribute__((ext_vector_type(8))) short bf16x8;
typedef __attribute__((ext_vector_type(4))) float f32x4;

static __device__ __forceinline__ unsigned short f2bf(float f) {
    unsigned u = __builtin_bit_cast(unsigned, f);
    u = (u + 0x7fffu + ((u >> 16) & 1u)) >> 16;  // RNE
    return (unsigned short)u;
}

static __device__ __forceinline__ bf16x8 cvt8(const float* p) {
    bf16x8 r;
    float4 a = *(const float4*)p;
    float4 b = *(const float4*)(p + 4);
    r[0] = (short)f2bf(a.x); r[1] = (short)f2bf(a.y);
    r[2] = (short)f2bf(a.z); r[3] = (short)f2bf(a.w);
    r[4] = (short)f2bf(b.x); r[5] = (short)f2bf(b.y);
    r[6] = (short)f2bf(b.z); r[7] = (short)f2bf(b.w);
    return r;
}

// Pack W [E,64] (fp32) into bf16 B-fragment layout: for k-block kb (32 k's),
// n-tile t (16 n's): lane L holds 8 elems W[kb*32 + (L>>4)*8 + j][t*16 + (L&15)]
__global__ void pack_w_kernel(const float* __restrict__ Wq,
                              const float* __restrict__ Wk,
                              const float* __restrict__ Wv,
                              unsigned short* __restrict__ Wt) {
    int tid = blockIdx.x * 256 + threadIdx.x;
    if (tid >= 3 * EE * HD) return;
    int w_idx = tid / (EE * HD);
    int rem = tid % (EE * HD);
    int kk = rem / HD, n = rem % HD;
    const float* Wsrc = (w_idx == 0) ? Wq : ((w_idx == 1) ? Wk : Wv);
    int kb = kk >> 5, kr = kk & 31, quad = kr >> 3, j = kr & 7;
    int t = n >> 4, c = n & 15;
    int lane = quad * 16 + c;
    Wt[w_idx * (EE * HD) + ((kb * 4 + t) * 64 + lane) * 8 + j] = f2bf(Wsrc[kk * HD + n]);
}

// QKV projection: 256 blocks x 256 thr; wave w owns 16 rows.
// Writes q,k as [B*S,64] bf16 row-major and v transposed vT[b][d][s] bf16.
__global__ __launch_bounds__(256) void qkv_kernel(
    const float* __restrict__ x,            // [B*S, E] fp32
    const unsigned short* __restrict__ Wt,  // packed bf16, 3*E*64
    unsigned short* __restrict__ q,
    unsigned short* __restrict__ k,
    unsigned short* __restrict__ vT) {
    const int lane = threadIdx.x & 63;
    const int wave = threadIdx.x >> 6;
    const int c = lane & 15, quad = lane >> 4;
    const int r0 = blockIdx.x * 64 + wave * 16;

    f32x4 acc[3][4];
    for (int a = 0; a < 3; ++a)
        for (int t = 0; t < 4; ++t) acc[a][t] = (f32x4){0.f, 0.f, 0.f, 0.f};

    const float* xrow = x + (size_t)(r0 + c) * EE;
    for (int kb = 0; kb < EE / 32; ++kb) {
        bf16x8 afrag = cvt8(xrow + kb * 32 + quad * 8);
        const unsigned short* wbase = Wt + kb * 2048 + lane * 8;
        for (int a = 0; a < 3; ++a) {
            const unsigned short* wa = wbase + a * (EE * HD);
            for (int t = 0; t < 4; ++t) {
                bf16x8 bfrag = *(const bf16x8*)(wa + t * 512);
                acc[a][t] = __builtin_amdgcn_mfma_f32_16x16x32_bf16(afrag, bfrag, acc[a][t], 0, 0, 0);
            }
        }
    }

    for (int t = 0; t < 4; ++t) {
        int col = t * 16 + c;
        for (int r = 0; r < 4; ++r) {
            int row = r0 + quad * 4 + r;
            q[(size_t)row * HD + col] = f2bf(acc[0][t][r]);
            k[(size_t)row * HD + col] = f2bf(acc[1][t][r]);
        }
        int row = r0 + quad * 4;
        int b_ = row >> 11, sb = row & (SS - 1);
        ushort4 pk;
        pk.x = f2bf(acc[2][t][0]);
        pk.y = f2bf(acc[2][t][1]);
        pk.z = f2bf(acc[2][t][2]);
        pk.w = f2bf(acc[2][t][3]);
        *(ushort4*)(vT + ((size_t)b_ * HD + col) * SS + sb) = pk;
    }
}

// Flash attention: grid (S/64, B), 256 thr (4 waves x 16 q-rows), 32-key tiles.
__global__ __launch_bounds__(256) void attn_kernel(
    const unsigned short* __restrict__ q,
    const unsigned short* __restrict__ k,
    const unsigned short* __restrict__ vT,
    const int* __restrict__ mask,
    float* __restrict__ out) {
    __shared__ __align__(16) unsigned short Ps[4][16 * 32];  // [wave][m][key], wave-private
    const int lane = threadIdx.x & 63;
    const int wave = threadIdx.x >> 6;
    const int c = lane & 15, quad = lane >> 4;
    const int b_ = blockIdx.y;
    const int q0 = blockIdx.x * 64;
    const int r0 = q0 + wave * 16;
    const float NEG = -1e30f;

    const unsigned short* qb = q + (size_t)b_ * SS * HD;
    const unsigned short* kbp = k + (size_t)b_ * SS * HD;
    const unsigned short* vb = vT + (size_t)b_ * HD * SS;
    const int* mb = mask + b_ * SS;

    bf16x8 aq0 = *(const bf16x8*)(qb + (size_t)(r0 + c) * HD + quad * 8);
    bf16x8 aq1 = *(const bf16x8*)(qb + (size_t)(r0 + c) * HD + 32 + quad * 8);

    f32x4 o[4];
    for (int t = 0; t < 4; ++t) o[t] = (f32x4){0.f, 0.f, 0.f, 0.f};
    float m_i[4], l_i[4];
    for (int r = 0; r < 4; ++r) { m_i[r] = NEG; l_i[r] = 0.f; }

    const int ntiles = q0 / 32 + 2;  // keys [0, q0+64) cover causal bound of this block
    for (int kt = 0; kt < ntiles; ++kt) {
        const int k0 = kt * 32;
        // ---- scores: S[16 x 32] = Q(16x64) . K^T ----
        float sc[2][4];
        for (int kg = 0; kg < 2; ++kg) {
            const unsigned short* krow = kbp + (size_t)(k0 + kg * 16 + c) * HD + quad * 8;
            bf16x8 b0 = *(const bf16x8*)(krow);
            bf16x8 b1 = *(const bf16x8*)(krow + 32);
            f32x4 accs = (f32x4){0.f, 0.f, 0.f, 0.f};
            accs = __builtin_amdgcn_mfma_f32_16x16x32_bf16(aq0, b0, accs, 0, 0, 0);
            accs = __builtin_amdgcn_mfma_f32_16x16x32_bf16(aq1, b1, accs, 0, 0, 0);
            int key = k0 + kg * 16 + c;
            int mv = mb[key];
            for (int r = 0; r < 4; ++r) {
                int row = r0 + quad * 4 + r;
                float v = accs[r] * 0.125f;  // HEAD^-0.5
                sc[kg][r] = ((key <= row) && (mv != 0)) ? v : NEG;
            }
        }
        // ---- online softmax per row (rows live across 16 lanes of a quad) ----
        float alpha[4];
        for (int r = 0; r < 4; ++r) {
            float mx = fmaxf(sc[0][r], sc[1][r]);
            mx = fmaxf(mx, __shfl_xor(mx, 1));
            mx = fmaxf(mx, __shfl_xor(mx, 2));
            mx = fmaxf(mx, __shfl_xor(mx, 4));
            mx = fmaxf(mx, __shfl_xor(mx, 8));
            float mnew = fmaxf(m_i[r], mx);
            alpha[r] = __expf(m_i[r] - mnew);
            m_i[r] = mnew;
            float p0 = __expf(sc[0][r] - mnew);
            float p1 = __expf(sc[1][r] - mnew);
            sc[0][r] = p0;
            sc[1][r] = p1;
            float sum = p0 + p1;
            sum += __shfl_xor(sum, 1);
            sum += __shfl_xor(sum, 2);
            sum += __shfl_xor(sum, 4);
            sum += __shfl_xor(sum, 8);
            l_i[r] = l_i[r] * alpha[r] + sum;
        }
        for (int t = 0; t < 4; ++t)
            for (int r = 0; r < 4; ++r) o[t][r] *= alpha[r];
        // ---- P: C/D layout -> A layout via wave-private LDS round-trip ----
        unsigned short* pbuf = &Ps[wave][0];
        for (int kg = 0; kg < 2; ++kg)
            for (int r = 0; r < 4; ++r)
                pbuf[(quad * 4 + r) * 32 + kg * 16 + c] = f2bf(sc[kg][r]);
        bf16x8 pa = *(const bf16x8*)(pbuf + c * 32 + quad * 8);
        // ---- O += P(16x32) . V(32x64); V B-frags contiguous from vT ----
        for (int t = 0; t < 4; ++t) {
            bf16x8 bv = *(const bf16x8*)(vb + (size_t)(t * 16 + c) * SS + k0 + quad * 8);
            o[t] = __builtin_amdgcn_mfma_f32_16x16x32_bf16(pa, bv, o[t], 0, 0, 0);
        }
    }

    for (int t = 0; t < 4; ++t)
        for (int r = 0; r < 4; ++r) {
            int row = r0 + quad * 4 + r;
            out[((size_t)b_ * SS + row) * HD + t * 16 + c] = o[t][r] / l_i[r];
        }
}

extern "C" void kernel_launch(void* const* d_in, const int* in_sizes, int n_in,
                              void* d_out, int out_size, void* d_ws, size_t ws_size,
                              hipStream_t stream) {
    const float* x = (const float*)d_in[0];
    const float* Wq = (const float*)d_in[1];
    const float* Wk = (const float*)d_in[2];
    const float* Wv = (const float*)d_in[3];
    const int* mask = (const int*)d_in[4];
    float* out = (float*)d_out;

    // workspace layout (bf16 elems): Wt[3*E*64] | q[B*S*64] | k[B*S*64] | vT[B*64*S]
    unsigned short* ws = (unsigned short*)d_ws;
    unsigned short* Wt = ws;
    unsigned short* q = Wt + 3 * EE * HD;
    unsigned short* kk = q + (size_t)BB * SS * HD;
    unsigned short* vT = kk + (size_t)BB * SS * HD;

    pack_w_kernel<<<dim3((3 * EE * HD + 255) / 256), dim3(256), 0, stream>>>(Wq, Wk, Wv, Wt);
    qkv_kernel<<<dim3(BB * SS / 64), dim3(256), 0, stream>>>(x, Wt, q, kk, vT);
    attn_kernel<<<dim3(SS / 64, BB), dim3(256), 0, stream>>>(q, kk, vT, mask, out);
}

// Round 3
// 166.917 us; speedup vs baseline: 1.0162x; 1.0162x over previous
//
#include <hip/hip_runtime.h>

#define BB 8
#define SS 2048
#define EE 512
#define HD 64
#define CHUNK 512
#define KT 64
#define NCH 4          // max chunks = SS/CHUNK
#define PST 72         // P LDS row stride (elems): 144B, 16B-aligned

typedef __attribute__((ext_vector_type(8))) short bf16x8;
typedef __attribute__((ext_vector_type(4))) float f32x4;

static __device__ __forceinline__ unsigned short f2bf(float f) {
    unsigned u = __builtin_bit_cast(unsigned, f);
    u = (u + 0x7fffu + ((u >> 16) & 1u)) >> 16;  // RNE
    return (unsigned short)u;
}
static __device__ __forceinline__ float bf2f(unsigned short h) {
    unsigned u = ((unsigned)h) << 16;
    return __builtin_bit_cast(float, u);
}
static __device__ __forceinline__ bf16x8 cvt8(const float* p) {
    bf16x8 r;
    float4 a = *(const float4*)p;
    float4 b = *(const float4*)(p + 4);
    r[0] = (short)f2bf(a.x); r[1] = (short)f2bf(a.y);
    r[2] = (short)f2bf(a.z); r[3] = (short)f2bf(a.w);
    r[4] = (short)f2bf(b.x); r[5] = (short)f2bf(b.y);
    r[6] = (short)f2bf(b.z); r[7] = (short)f2bf(b.w);
    return r;
}

// Pack W [E,64] (fp32) into bf16 B-fragment layout.
__global__ void pack_w_kernel(const float* __restrict__ Wq,
                              const float* __restrict__ Wk,
                              const float* __restrict__ Wv,
                              unsigned short* __restrict__ Wt) {
    int tid = blockIdx.x * 256 + threadIdx.x;
    if (tid >= 3 * EE * HD) return;
    int w_idx = tid / (EE * HD);
    int rem = tid % (EE * HD);
    int kk = rem / HD, n = rem % HD;
    const float* Wsrc = (w_idx == 0) ? Wq : ((w_idx == 1) ? Wk : Wv);
    int kb = kk >> 5, kr = kk & 31, quad = kr >> 3, j = kr & 7;
    int t = n >> 4, c = n & 15;
    int lane = quad * 16 + c;
    Wt[w_idx * (EE * HD) + ((kb * 4 + t) * 64 + lane) * 8 + j] = f2bf(Wsrc[kk * HD + n]);
}

// QKV: grid B*S/16 blocks x 192 thr; wave w computes matrix w (q/k/v) for 16 rows.
// 3072 waves (~12/CU) vs previous 1024 (4/CU) -> latency hiding.
__global__ __launch_bounds__(192) void qkv_kernel(
    const float* __restrict__ x,            // [B*S, E] fp32
    const unsigned short* __restrict__ Wt,  // packed bf16, 3*E*64
    unsigned short* __restrict__ q,
    unsigned short* __restrict__ k,
    unsigned short* __restrict__ vT) {
    const int lane = threadIdx.x & 63;
    const int wave = threadIdx.x >> 6;  // 0..2 = q,k,v
    const int c = lane & 15, quad = lane >> 4;
    const int r0 = blockIdx.x * 16;

    f32x4 acc[4];
    for (int t = 0; t < 4; ++t) acc[t] = (f32x4){0.f, 0.f, 0.f, 0.f};

    const float* xrow = x + (size_t)(r0 + c) * EE;
    const unsigned short* wm = Wt + wave * (EE * HD);
#pragma unroll
    for (int kb = 0; kb < EE / 32; ++kb) {
        bf16x8 afrag = cvt8(xrow + kb * 32 + quad * 8);
        const unsigned short* wbase = wm + kb * 2048 + lane * 8;
        for (int t = 0; t < 4; ++t) {
            bf16x8 bfrag = *(const bf16x8*)(wbase + t * 512);
            acc[t] = __builtin_amdgcn_mfma_f32_16x16x32_bf16(afrag, bfrag, acc[t], 0, 0, 0);
        }
    }

    if (wave < 2) {
        unsigned short* dst = wave ? k : q;
        for (int t = 0; t < 4; ++t) {
            int col = t * 16 + c;
            for (int r = 0; r < 4; ++r)
                dst[(size_t)(r0 + quad * 4 + r) * HD + col] = f2bf(acc[t][r]);
        }
    } else {
        int row = r0 + quad * 4;
        int b_ = row >> 11, sb = row & (SS - 1);
        for (int t = 0; t < 4; ++t) {
            int col = t * 16 + c;
            ushort4 pk;
            pk.x = f2bf(acc[t][0]);
            pk.y = f2bf(acc[t][1]);
            pk.z = f2bf(acc[t][2]);
            pk.w = f2bf(acc[t][3]);
            *(ushort4*)(vT + ((size_t)b_ * HD + col) * SS + sb) = pk;
        }
    }
}

// Split-K flash attention partial: grid (NCH, S/64, B), 256 thr.
// Block (cx,qb,b) processes keys [cx*512, min(cx*512+512, qb*64+64)) for 64 q rows.
// Stores per-chunk normalized O (bf16) + m,l (fp32).
__global__ __launch_bounds__(256) void attn_kernel(
    const unsigned short* __restrict__ q,
    const unsigned short* __restrict__ k,
    const unsigned short* __restrict__ vT,
    const int* __restrict__ mask,
    unsigned short* __restrict__ po,   // [B][32][NCH][64 rows][64 d] bf16
    float* __restrict__ pml) {         // [B][32][NCH][64 rows][2] fp32
    __shared__ __align__(16) unsigned short Ps[4][16 * PST];
    const int lane = threadIdx.x & 63;
    const int wave = threadIdx.x >> 6;
    const int c = lane & 15, quad = lane >> 4;
    const int cx = blockIdx.x, qb = blockIdx.y, b_ = blockIdx.z;
    const int q0 = qb * 64;
    const int kstart = cx * CHUNK;
    const int kend = min(kstart + CHUNK, q0 + 64);
    if (kstart >= kend) return;
    const int r0 = q0 + wave * 16;
    const float MINIT = -1e30f;
    const float MASKV = -3e38f;  // < MINIT so fully-masked chunk gives p=0, l=0

    const unsigned short* qb_p = q + (size_t)b_ * SS * HD;
    const unsigned short* kb_p = k + (size_t)b_ * SS * HD;
    const unsigned short* vb = vT + (size_t)b_ * HD * SS;
    const int* mb = mask + b_ * SS;

    bf16x8 aq0 = *(const bf16x8*)(qb_p + (size_t)(r0 + c) * HD + quad * 8);
    bf16x8 aq1 = *(const bf16x8*)(qb_p + (size_t)(r0 + c) * HD + 32 + quad * 8);

    f32x4 o[4];
    for (int t = 0; t < 4; ++t) o[t] = (f32x4){0.f, 0.f, 0.f, 0.f};
    float m_i[4], l_i[4];
    for (int r = 0; r < 4; ++r) { m_i[r] = MINIT; l_i[r] = 0.f; }

    const int ntiles = (kend - kstart) / KT;
    for (int kt = 0; kt < ntiles; ++kt) {
        const int k0 = kstart + kt * KT;
        float sc[4][4];
#pragma unroll
        for (int kg = 0; kg < 4; ++kg) {
            const unsigned short* krow = kb_p + (size_t)(k0 + kg * 16 + c) * HD + quad * 8;
            bf16x8 b0 = *(const bf16x8*)(krow);
            bf16x8 b1 = *(const bf16x8*)(krow + 32);
            f32x4 accs = (f32x4){0.f, 0.f, 0.f, 0.f};
            accs = __builtin_amdgcn_mfma_f32_16x16x32_bf16(aq0, b0, accs, 0, 0, 0);
            accs = __builtin_amdgcn_mfma_f32_16x16x32_bf16(aq1, b1, accs, 0, 0, 0);
            int key = k0 + kg * 16 + c;
            int mv = mb[key];
            for (int r = 0; r < 4; ++r) {
                int row = r0 + quad * 4 + r;
                float v = accs[r] * 0.125f;  // HEAD^-0.5
                sc[kg][r] = ((key <= row) && (mv != 0)) ? v : MASKV;
            }
        }
        float alpha[4];
#pragma unroll
        for (int r = 0; r < 4; ++r) {
            float mx = fmaxf(fmaxf(sc[0][r], sc[1][r]), fmaxf(sc[2][r], sc[3][r]));
            mx = fmaxf(mx, __shfl_xor(mx, 1));
            mx = fmaxf(mx, __shfl_xor(mx, 2));
            mx = fmaxf(mx, __shfl_xor(mx, 4));
            mx = fmaxf(mx, __shfl_xor(mx, 8));
            float mnew = fmaxf(m_i[r], mx);
            alpha[r] = __expf(m_i[r] - mnew);
            m_i[r] = mnew;
            float sum = 0.f;
            for (int kg = 0; kg < 4; ++kg) {
                float p = __expf(sc[kg][r] - mnew);  // masked: exp(-3e38-x)=0
                sc[kg][r] = p;
                sum += p;
            }
            sum += __shfl_xor(sum, 1);
            sum += __shfl_xor(sum, 2);
            sum += __shfl_xor(sum, 4);
            sum += __shfl_xor(sum, 8);
            l_i[r] = l_i[r] * alpha[r] + sum;
        }
        for (int t = 0; t < 4; ++t)
            for (int r = 0; r < 4; ++r) o[t][r] *= alpha[r];
        // P: C/D layout -> A layout via wave-private LDS (stride PST, 16B-aligned reads)
        unsigned short* pbuf = &Ps[wave][0];
        for (int kg = 0; kg < 4; ++kg)
            for (int r = 0; r < 4; ++r)
                pbuf[(quad * 4 + r) * PST + kg * 16 + c] = f2bf(sc[kg][r]);
        bf16x8 pa0 = *(const bf16x8*)(pbuf + c * PST + quad * 8);
        bf16x8 pa1 = *(const bf16x8*)(pbuf + c * PST + 32 + quad * 8);
        for (int t = 0; t < 4; ++t) {
            const unsigned short* vrow = vb + (size_t)(t * 16 + c) * SS + k0 + quad * 8;
            bf16x8 bv0 = *(const bf16x8*)(vrow);
            bf16x8 bv1 = *(const bf16x8*)(vrow + 32);
            o[t] = __builtin_amdgcn_mfma_f32_16x16x32_bf16(pa0, bv0, o[t], 0, 0, 0);
            o[t] = __builtin_amdgcn_mfma_f32_16x16x32_bf16(pa1, bv1, o[t], 0, 0, 0);
        }
    }

    const size_t base = ((size_t)(b_ * 32 + qb) * NCH + cx);
    for (int r = 0; r < 4; ++r) {
        int rl = wave * 16 + quad * 4 + r;
        float l = l_i[r];
        float inv = (l > 0.f) ? 1.f / l : 0.f;
        for (int t = 0; t < 4; ++t)
            po[base * 4096 + (size_t)rl * 64 + t * 16 + c] = f2bf(o[r > -1 ? t : t][r] * inv);
        if (c == 0) {
            pml[(base * 64 + rl) * 2 + 0] = m_i[r];
            pml[(base * 64 + rl) * 2 + 1] = l;
        }
    }
}

// Combine: out[row][d] = sum_c w_c * o_c[d],  w_c = l_c exp(m_c - M) / L.
__global__ __launch_bounds__(256) void combine_kernel(
    const unsigned short* __restrict__ po,
    const float* __restrict__ pml,
    float* __restrict__ out) {
    int t = blockIdx.x * 256 + threadIdx.x;
    if (t >= BB * SS * HD) return;
    int d = t & 63;
    int row_g = t >> 6;
    int b_ = row_g >> 11, row = row_g & (SS - 1);
    int qb = row >> 6, rl = row & 63;
    int nch = row / CHUNK + 1;
    size_t base = (size_t)(b_ * 32 + qb) * NCH;
    float m_c[NCH], l_c[NCH];
    float M = -3e38f;
    for (int c = 0; c < nch; ++c) {
        m_c[c] = pml[((base + c) * 64 + rl) * 2 + 0];
        l_c[c] = pml[((base + c) * 64 + rl) * 2 + 1];
        M = fmaxf(M, m_c[c]);
    }
    float L = 0.f, acc = 0.f;
    for (int c = 0; c < nch; ++c) {
        float w = l_c[c] * __expf(m_c[c] - M);
        L += w;
        acc += w * bf2f(po[(base + c) * 4096 + (size_t)rl * 64 + d]);
    }
    out[t] = acc / L;
}

extern "C" void kernel_launch(void* const* d_in, const int* in_sizes, int n_in,
                              void* d_out, int out_size, void* d_ws, size_t ws_size,
                              hipStream_t stream) {
    const float* x = (const float*)d_in[0];
    const float* Wq = (const float*)d_in[1];
    const float* Wk = (const float*)d_in[2];
    const float* Wv = (const float*)d_in[3];
    const int* mask = (const int*)d_in[4];
    float* out = (float*)d_out;

    // ws layout (bf16 elems unless noted):
    // Wt[3*E*64] | q[B*S*64] | k[B*S*64] | vT[B*64*S] | po[B*32*NCH*4096] | pml fp32
    unsigned short* ws = (unsigned short*)d_ws;
    unsigned short* Wt = ws;
    unsigned short* q = Wt + 3 * EE * HD;
    unsigned short* kk = q + (size_t)BB * SS * HD;
    unsigned short* vT = kk + (size_t)BB * SS * HD;
    unsigned short* po = vT + (size_t)BB * SS * HD;
    float* pml = (float*)(po + (size_t)BB * 32 * NCH * 4096);

    pack_w_kernel<<<dim3((3 * EE * HD + 255) / 256), dim3(256), 0, stream>>>(Wq, Wk, Wv, Wt);
    qkv_kernel<<<dim3(BB * SS / 16), dim3(192), 0, stream>>>(x, Wt, q, kk, vT);
    attn_kernel<<<dim3(NCH, SS / 64, BB), dim3(256), 0, stream>>>(q, kk, vT, mask, po, pml);
    combine_kernel<<<dim3((BB * SS * HD + 255) / 256), dim3(256), 0, stream>>>(po, pml, out);
}